// Round 7
// baseline (622.061 us; speedup 1.0000x reference)
//
#include <hip/hip_runtime.h>
#include <hip/hip_bf16.h>
#include <math.h>

namespace {

constexpr int B = 8, T = 2048, D = 256, H = 4, HD = 64, FF = 1024;
constexpr float QSCALE = 0.18033688f;   // 0.125 * log2(e)

typedef __attribute__((ext_vector_type(8))) short short8;
typedef __attribute__((ext_vector_type(4))) short s16x4;
typedef __attribute__((ext_vector_type(4))) float f32x4;

__device__ __forceinline__ short f2bf(float f) {
    __hip_bfloat16 h = __float2bfloat16(f);
    return *reinterpret_cast<short*>(&h);
}
__device__ __forceinline__ float bf2f(short s) {
    union { unsigned u; float f; } c;
    c.u = ((unsigned)(unsigned short)s) << 16;
    return c.f;
}
__device__ __forceinline__ float exp2a(float x) {
    float r; asm("v_exp_f32 %0, %1" : "=v"(r) : "v"(x)); return r;
}
__device__ __forceinline__ unsigned cvtpk(float lo, float hi) {
    unsigned r; asm("v_cvt_pk_bf16_f32 %0, %1, %2" : "=v"(r) : "v"(lo), "v"(hi)); return r;
}

// ---------------- K0: fp32 -> bf16 conversions (x + 4 weight matrices) -----
__global__ __launch_bounds__(256) void k_cvt(
        const float* __restrict__ x,  const float* __restrict__ wq,
        const float* __restrict__ wo, const float* __restrict__ w1,
        const float* __restrict__ w2,
        short* __restrict__ x16,  short* __restrict__ wq16,
        short* __restrict__ wo16, short* __restrict__ w116,
        short* __restrict__ w216) {
    const int N0 = 524288, N1 = 24576, N2 = 8192, N3 = 32768, N4 = 32768;
    const int total = N0 + N1 + N2 + N3 + N4;
    for (int i = blockIdx.x*256 + threadIdx.x; i < total; i += gridDim.x*256) {
        const float* s; short* d; int j = i;
        if (j < N0) { s = x; d = x16; }
        else { j -= N0;
            if (j < N1) { s = wq; d = wq16; }
            else { j -= N1;
                if (j < N2) { s = wo; d = wo16; }
                else { j -= N2;
                    if (j < N3) { s = w1; d = w116; }
                    else { j -= N3; s = w2; d = w216; }
                }
            }
        }
        float4 a = ((const float4*)s)[j*2], b2 = ((const float4*)s)[j*2+1];
        short8 o;
        o[0]=f2bf(a.x);  o[1]=f2bf(a.y);  o[2]=f2bf(a.z);  o[3]=f2bf(a.w);
        o[4]=f2bf(b2.x); o[5]=f2bf(b2.y); o[6]=f2bf(b2.z); o[7]=f2bf(b2.w);
        ((short8*)d)[j] = o;
    }
}

// ---------------- K_GEMM: C = A * W^T, bf16 MFMA, NO LDS in K-loop ---------
template<int MODE>
__global__ __launch_bounds__(256) void k_gemm(
        const short* __restrict__ A, const short* __restrict__ W,
        const float* __restrict__ bias, const int K,
        short* __restrict__ oq, short* __restrict__ ok, short* __restrict__ ov,
        float* __restrict__ of, short* __restrict__ o16) {
    __shared__ float Cs[64][68];
    const int tid = threadIdx.x;
    const int w = tid >> 6, lane = tid & 63;
    const int qr = lane & 15, g = lane >> 4;
    const int wm = w >> 1, wn = w & 1;
    const int m0 = blockIdx.x * 64;
    const int n0 = blockIdx.y * 64;

    const short* Am0 = A + (size_t)(m0 + wm*32 + qr) * K + g*8;
    const short* Am1 = A + (size_t)(m0 + wm*32 + 16 + qr) * K + g*8;
    const short* Wn0 = W + (size_t)(n0 + wn*32 + qr) * K + g*8;
    const short* Wn1 = W + (size_t)(n0 + wn*32 + 16 + qr) * K + g*8;

    f32x4 acc[2][2];
    #pragma unroll
    for (int i = 0; i < 2; i++)
        #pragma unroll
        for (int j = 0; j < 2; j++) acc[i][j] = (f32x4){0.f, 0.f, 0.f, 0.f};

    for (int k0 = 0; k0 < K; k0 += 64) {
        #pragma unroll
        for (int kk = 0; kk < 2; kk++) {
            const int off = k0 + kk*32;
            short8 a0 = *(const short8*)(Am0 + off);
            short8 a1 = *(const short8*)(Am1 + off);
            short8 b0 = *(const short8*)(Wn0 + off);
            short8 b1 = *(const short8*)(Wn1 + off);
            acc[0][0] = __builtin_amdgcn_mfma_f32_16x16x32_bf16(a0, b0, acc[0][0], 0, 0, 0);
            acc[0][1] = __builtin_amdgcn_mfma_f32_16x16x32_bf16(a0, b1, acc[0][1], 0, 0, 0);
            acc[1][0] = __builtin_amdgcn_mfma_f32_16x16x32_bf16(a1, b0, acc[1][0], 0, 0, 0);
            acc[1][1] = __builtin_amdgcn_mfma_f32_16x16x32_bf16(a1, b1, acc[1][1], 0, 0, 0);
        }
    }

    const int b = m0 >> 11;
    const int tl0 = m0 & (T - 1);

    if (MODE == 0 && blockIdx.y >= 8) {
        const int h = (int)blockIdx.y - 8;
        #pragma unroll
        for (int fm = 0; fm < 2; fm++) {
            const int tbase = tl0 + wm*32 + fm*16 + g*4;
            #pragma unroll
            for (int fn = 0; fn < 2; fn++) {
                const int d = wn*32 + fn*16 + qr;
                const float bv = bias[n0 + d];
                s16x4 pk;
                #pragma unroll
                for (int r = 0; r < 4; r++) pk[r] = f2bf(acc[fm][fn][r] + bv);
                *(s16x4*)&ov[((size_t)(b*H + h)*HD + d)*T + tbase] = pk;
            }
        }
        return;
    }

    #pragma unroll
    for (int fm = 0; fm < 2; fm++)
        #pragma unroll
        for (int fn = 0; fn < 2; fn++)
            #pragma unroll
            for (int r = 0; r < 4; r++)
                Cs[wm*32 + fm*16 + g*4 + r][wn*32 + fn*16 + qr] = acc[fm][fn][r];
    __syncthreads();
    const int row = tid >> 2, c0 = (tid & 3) * 16;
    float vals[16];
    #pragma unroll
    for (int j = 0; j < 16; j++) vals[j] = Cs[row][c0 + j] + bias[n0 + c0 + j];

    if (MODE == 0) {
        const int by = blockIdx.y;
        short* dst = (by < 4) ? oq : ok;
        const float qs = (by < 4) ? QSCALE : 1.0f;
        const int h = by & 3;
        short8 s0, s1;
        #pragma unroll
        for (int j = 0; j < 8; j++) { s0[j] = f2bf(vals[j]*qs); s1[j] = f2bf(vals[8+j]*qs); }
        short* p = dst + ((size_t)(b*H + h)*T + tl0 + row)*HD + c0;
        *(short8*)p = s0;
        *(short8*)(p + 8) = s1;
    } else if (MODE == 1 || MODE == 3) {
        float* p = of + (size_t)(m0 + row)*256 + n0 + c0;
        #pragma unroll
        for (int jj = 0; jj < 4; jj++) *(float4*)(p + jj*4) = *(float4*)&vals[jj*4];
    } else {
        short8 s0, s1;
        #pragma unroll
        for (int j = 0; j < 8; j++) {
            s0[j] = f2bf(fmaxf(vals[j], 0.f));
            s1[j] = f2bf(fmaxf(vals[8+j], 0.f));
        }
        short* p = o16 + (size_t)(m0 + row)*1024 + n0 + c0;
        *(short8*)p = s0;
        *(short8*)(p + 8) = s1;
    }
}

// ---------------- FL: l-only pass. No LDS, no barriers. Full T loop. -------
__global__ __launch_bounds__(256) void k_flashL(
        const short* __restrict__ qb, const short* __restrict__ kb,
        const float* __restrict__ mask, float* __restrict__ liout) {
    const int tid = threadIdx.x;
    const int w = tid >> 6, lane = tid & 63;
    const int qr = lane & 15, g = lane >> 4;
    const int qt = blockIdx.x, h = blockIdx.y, b = blockIdx.z;
    const int bh = b*H + h;
    const int q0 = qt*64 + w*16;

    const short* qg = qb + ((size_t)bh * T + q0) * HD;
    const short8 qf0 = *(const short8*)(qg + qr*HD + g*8);
    const short8 qf1 = *(const short8*)(qg + qr*HD + 32 + g*8);
    const short* kg0 = kb + (size_t)bh * T * HD + g*8;
    const float* mg  = mask + (size_t)b * T;

    float lrun = 0.f;
    for (int kt = 0; kt < 32; kt++) {
        #pragma unroll
        for (int t4 = 0; t4 < 4; t4++) {
            const int key0 = kt*64 + t4*16;
            const float4 mv4 = *(const float4*)(mg + key0 + 4*g);
            f32x4 sa = (f32x4){ (mv4.x > 0.5f) ? -1e9f : 0.f,
                                (mv4.y > 0.5f) ? -1e9f : 0.f,
                                (mv4.z > 0.5f) ? -1e9f : 0.f,
                                (mv4.w > 0.5f) ? -1e9f : 0.f };
            const short* kp = kg0 + (size_t)(key0 + qr) * HD;
            short8 kf0 = *(const short8*)kp;
            short8 kf1 = *(const short8*)(kp + 32);
            sa = __builtin_amdgcn_mfma_f32_16x16x32_bf16(kf0, qf0, sa, 0, 0, 0);
            sa = __builtin_amdgcn_mfma_f32_16x16x32_bf16(kf1, qf1, sa, 0, 0, 0);
            lrun += (exp2a(sa[0]) + exp2a(sa[1])) + (exp2a(sa[2]) + exp2a(sa[3]));
        }
    }
    lrun += __shfl_xor(lrun, 16, 64);
    lrun += __shfl_xor(lrun, 32, 64);
    if (g == 0)
        liout[(size_t)bh*T + q0 + qr] = -__log2f(lrun);
}

// ---------------- FPV: PV + colsum, split-K, normalized P, no barriers -----
__global__ __launch_bounds__(256) void k_flashPV(
        const short* __restrict__ qb, const short* __restrict__ kb,
        const short* __restrict__ vtb, const float* __restrict__ mask,
        const float* __restrict__ liout,
        short* __restrict__ opart, float* __restrict__ part4) {
    __shared__ short Ps[4][16][68];   // per-wave P[q][key] bf16 (normalized)

    const int tid = threadIdx.x;
    const int w = tid >> 6, lane = tid & 63;
    const int qr = lane & 15, g = lane >> 4;
    const int kh = blockIdx.x & 1, qt = blockIdx.x >> 1;
    const int h = blockIdx.y, b = blockIdx.z;
    const int bh = b*H + h;
    const int q0 = qt*64 + w*16;

    const short* qg = qb + ((size_t)bh * T + q0) * HD;
    const short8 qf0 = *(const short8*)(qg + qr*HD + g*8);
    const short8 qf1 = *(const short8*)(qg + qr*HD + 32 + g*8);
    const float li = liout[(size_t)bh*T + q0 + qr];   // log2(1/l), per-lane scalar

    const short* kg0 = kb + (size_t)bh * T * HD + (size_t)kh*1024*HD + g*8;
    const short* vg0 = vtb + (size_t)bh * HD * T + kh*1024;
    const float* mg  = mask + (size_t)b * T + kh*1024;

    f32x4 oa[4];
    #pragma unroll
    for (int i = 0; i < 4; i++) oa[i] = (f32x4){0.f, 0.f, 0.f, 0.f};

    float* prow = part4 + ((size_t)((bh*32 + qt)*4 + w))*T + kh*1024 + lane;

    for (int kt = 0; kt < 16; kt++) {
        float p[4][4];
        #pragma unroll
        for (int t4 = 0; t4 < 4; t4++) {
            const int key0 = kt*64 + t4*16;
            const float4 mv4 = *(const float4*)(mg + key0 + 4*g);
            f32x4 sa = (f32x4){ ((mv4.x > 0.5f) ? -1e9f : 0.f) + li,
                                ((mv4.y > 0.5f) ? -1e9f : 0.f) + li,
                                ((mv4.z > 0.5f) ? -1e9f : 0.f) + li,
                                ((mv4.w > 0.5f) ? -1e9f : 0.f) + li };
            const short* kp = kg0 + (size_t)(key0 + qr) * HD;
            short8 kf0 = *(const short8*)kp;
            short8 kf1 = *(const short8*)(kp + 32);
            sa = __builtin_amdgcn_mfma_f32_16x16x32_bf16(kf0, qf0, sa, 0, 0, 0);
            sa = __builtin_amdgcn_mfma_f32_16x16x32_bf16(kf1, qf1, sa, 0, 0, 0);
            p[t4][0] = exp2a(sa[0]);
            p[t4][1] = exp2a(sa[1]);
            p[t4][2] = exp2a(sa[2]);
            p[t4][3] = exp2a(sa[3]);
        }
        #pragma unroll
        for (int t4 = 0; t4 < 4; t4++) {
            union { unsigned u[2]; s16x4 s; } cv;
            cv.u[0] = cvtpk(p[t4][0], p[t4][1]);
            cv.u[1] = cvtpk(p[t4][2], p[t4][3]);
            *(s16x4*)&Ps[w][qr][t4*16 + 4*g] = cv.s;
        }
        asm volatile("" ::: "memory");   // order punned wave-local LDS RAW (R2 lesson)
        const short8 pa0 = *(const short8*)&Ps[w][qr][g*8];
        const short8 pa1 = *(const short8*)&Ps[w][qr][g*8 + 32];

        #pragma unroll
        for (int nt = 0; nt < 4; nt++) {
            const short* vp = vg0 + (size_t)(nt*16 + qr)*T + kt*64 + g*8;
            short8 vf0 = *(const short8*)vp;
            short8 vf1 = *(const short8*)(vp + 32);
            oa[nt] = __builtin_amdgcn_mfma_f32_16x16x32_bf16(vf0, pa0, oa[nt], 0, 0, 0);
            oa[nt] = __builtin_amdgcn_mfma_f32_16x16x32_bf16(vf1, pa1, oa[nt], 0, 0, 0);
        }
        // colsum over this wave's 16 q's for key = lane (broadcast-pair reads)
        float cs = 0.f;
        #pragma unroll
        for (int q = 0; q < 16; q++) cs += bf2f(Ps[w][q][lane]);
        prow[kt*64] = cs;
    }

    const size_t obase = ((size_t)(kh*32 + bh)*2048 + q0 + qr) * 64;
    #pragma unroll
    for (int nt = 0; nt < 4; nt++) {
        s16x4 pk;
        #pragma unroll
        for (int r = 0; r < 4; r++) pk[r] = f2bf(oa[nt][r]);
        *(s16x4*)&opart[obase + nt*16 + 4*g] = pk;
    }
}

// ---------------- COMB: O = O0 + O1 (already normalized) -> attn16 ---------
__global__ __launch_bounds__(256) void k_comb(
        const short* __restrict__ opart, short* __restrict__ attnb) {
    const int j = blockIdx.x*256 + threadIdx.x;
    const size_t flat = (size_t)j * 8;
    const int d0 = (int)(flat & 63);
    const int q  = (int)((flat >> 6) & 2047);
    const int bh = (int)(flat >> 17);
    short8 o0 = *(const short8*)&opart[flat];
    short8 o1 = *(const short8*)&opart[flat + (size_t)4194304];
    short8 r;
    #pragma unroll
    for (int i = 0; i < 8; i++) r[i] = f2bf(bf2f(o0[i]) + bf2f(o1[i]));
    const int b = bh >> 2, h = bh & 3;
    *(short8*)&attnb[((size_t)(b*2048 + q))*256 + h*64 + d0] = r;
}

// ---------------- K_RED: red[b][k] = sum over 512 (h,qt,w) rows ------------
__global__ __launch_bounds__(256) void k_red(
        const float* __restrict__ part4, float* __restrict__ red) {
    __shared__ float s[128];
    const int b = blockIdx.y, kc = blockIdx.x;
    const int tid = threadIdx.x;
    const int c = tid & 127, half = tid >> 7;
    const int k = kc*128 + c;
    const float* pb = part4 + ((size_t)(b*512 + half*256))*T + k;
    float acc = 0.f;
    #pragma unroll 8
    for (int r = 0; r < 256; r++) acc += pb[(size_t)r*T];
    if (half) s[c] = acc;
    __syncthreads();
    if (!half) red[(size_t)b*T + k] = acc + s[c];
}

// ---------------- K3: halting = softmax(red/H + mask*(-1e10)) --------------
__global__ __launch_bounds__(256) void k_halt(
        const float* __restrict__ red, const float* __restrict__ mask,
        float* __restrict__ outh) {
    __shared__ float redm[4], reds[4];
    const int b = blockIdx.x, tid = threadIdx.x;
    const float* mg = mask + (size_t)b * T;
    float v[8];
    float M = -3e38f;
    #pragma unroll
    for (int i = 0; i < 8; i++) {
        v[i] = red[(size_t)b*T + tid + i*256]*0.25f + mg[tid + i*256]*(-1e10f);
        M = fmaxf(M, v[i]);
    }
    #pragma unroll
    for (int off = 1; off < 64; off <<= 1) M = fmaxf(M, __shfl_xor(M, off, 64));
    const int wv = tid >> 6, lane = tid & 63;
    if (lane == 0) redm[wv] = M;
    __syncthreads();
    M = fmaxf(fmaxf(redm[0], redm[1]), fmaxf(redm[2], redm[3]));
    float S = 0.f;
    #pragma unroll
    for (int i = 0; i < 8; i++) { v[i] = __expf(v[i] - M); S += v[i]; }
    #pragma unroll
    for (int off = 1; off < 64; off <<= 1) S += __shfl_xor(S, off, 64);
    if (lane == 0) reds[wv] = S;
    __syncthreads();
    const float invS = 1.f / (reds[0] + reds[1] + reds[2] + reds[3]);
    #pragma unroll
    for (int i = 0; i < 8; i++) outh[(size_t)b*T + tid + i*256] = v[i]*invS;
}

// ---------------- K_LN: y = LN(a + bsrc)*g + be; optional bf16 copy --------
__global__ __launch_bounds__(256) void k_ln(
        const float* __restrict__ a, const float* __restrict__ bsrc,
        const float* __restrict__ g, const float* __restrict__ be,
        float* __restrict__ yf, short* __restrict__ y16) {
    __shared__ float s[16][D];
    const int tid = threadIdx.x;
    const size_t row0 = (size_t)blockIdx.x * 16;
    const float4* ag = (const float4*)(a + row0*D);
    const float4* bg = (const float4*)(bsrc + row0*D);
    #pragma unroll
    for (int i = 0; i < 4; i++) {
        float4 av = ag[tid + i*256], bv = bg[tid + i*256];
        float4 sv = {av.x+bv.x, av.y+bv.y, av.z+bv.z, av.w+bv.w};
        ((float4*)&s[0][0])[tid + i*256] = sv;
    }
    __syncthreads();
    const int wv = tid >> 6, lane = tid & 63;
    float gvv[4], bvv[4];
    #pragma unroll
    for (int s2 = 0; s2 < 4; s2++) { gvv[s2] = g[lane + 64*s2]; bvv[s2] = be[lane + 64*s2]; }
    #pragma unroll
    for (int rr = 0; rr < 4; rr++) {
        const int r = wv*4 + rr;
        float x0 = s[r][lane],     x1 = s[r][lane+64];
        float x2 = s[r][lane+128], x3 = s[r][lane+192];
        float sum = x0+x1+x2+x3;
        float ssq = x0*x0 + x1*x1 + x2*x2 + x3*x3;
        #pragma unroll
        for (int off = 1; off < 64; off <<= 1) {
            sum += __shfl_xor(sum, off, 64);
            ssq += __shfl_xor(ssq, off, 64);
        }
        const float mu = sum * (1.f/256.f);
        const float rs = rsqrtf(ssq*(1.f/256.f) - mu*mu + 1e-5f);
        float y0 = (x0 - mu)*rs*gvv[0] + bvv[0];
        float y1 = (x1 - mu)*rs*gvv[1] + bvv[1];
        float y2 = (x2 - mu)*rs*gvv[2] + bvv[2];
        float y3 = (x3 - mu)*rs*gvv[3] + bvv[3];
        float* yp = yf + (row0 + r)*D;
        yp[lane]     = y0;
        yp[lane+64]  = y1;
        yp[lane+128] = y2;
        yp[lane+192] = y3;
        if (y16) {
            short* hp = y16 + (row0 + r)*D;
            hp[lane]     = f2bf(y0);
            hp[lane+64]  = f2bf(y1);
            hp[lane+128] = f2bf(y2);
            hp[lane+192] = f2bf(y3);
        }
    }
}

} // namespace

extern "C" void kernel_launch(void* const* d_in, const int* in_sizes, int n_in,
                              void* d_out, int out_size, void* d_ws, size_t ws_size,
                              hipStream_t stream) {
    (void)in_sizes; (void)n_in; (void)out_size; (void)ws_size;
    const float* x    = (const float*)d_in[0];
    const float* mask = (const float*)d_in[1];
    const float* Wqkv = (const float*)d_in[2];
    const float* bqkv = (const float*)d_in[3];
    const float* Wo   = (const float*)d_in[4];
    const float* bo   = (const float*)d_in[5];
    const float* W1   = (const float*)d_in[6];
    const float* b1   = (const float*)d_in[7];
    const float* W2   = (const float*)d_in[8];
    const float* b2   = (const float*)d_in[9];
    const float* g1   = (const float*)d_in[10];
    const float* be1  = (const float*)d_in[11];
    const float* g2   = (const float*)d_in[12];
    const float* be2  = (const float*)d_in[13];

    float* out  = (float*)d_out;
    char*  wsb  = (char*)d_ws;
    const size_t MB = 1024*1024;

    // liveness-overlaid layout, max 91 MiB (>=100 MiB proven in R1)
    short* qb16   = (short*)(wsb + 0*MB);            // gemm0 -> flashPV
    short* kb16   = (short*)(wsb + 8*MB);            // gemm0 -> flashPV
    short* vt16   = (short*)(wsb + 16*MB);           // gemm0 -> flashPV
    short* x16    = (short*)(wsb + 24*MB);           // cvt -> gemm0
    short* attn16 = (short*)(wsb + 24*MB);           // comb -> gemm1 (x16 dead)
    float* part4  = (float*)(wsb + 32*MB);           // 32MB, flashPV -> red
    short* mid16  = (short*)(wsb + 32*MB);           // gemm2 -> gemm3 (after red)
    short* opart  = (short*)(wsb + 64*MB);           // 16MB, flashPV -> comb
    float* hb     = (float*)(wsb + 64*MB);           // ln1 -> ln2 (opart dead)
    short* h16    = (short*)(wsb + 80*MB);           // ln1 -> gemm2
    float* liout  = (float*)(wsb + 88*MB);           // 256KB, flashL -> flashPV
    float* redb   = (float*)(wsb + 88*MB + 262144);  // 64KB, red -> halt
    short* wq16   = (short*)(wsb + 89*MB);
    short* wo16   = (short*)(wsb + 89*MB + 393216);
    short* w116   = (short*)(wsb + 89*MB + 524288);
    short* w216   = (short*)(wsb + 89*MB + 1048576);
    float* po     = (float*)(wsb + 0*MB);            // gemm1 -> ln1 (q/k dead)
    float* fo     = (float*)(wsb + 0*MB);            // gemm3 -> ln2 (po dead)
    float* outh   = out + (size_t)B*T*D;

    k_cvt    <<<dim3(1024),        256, 0, stream>>>(x, Wqkv, Wo, W1, W2,
                                                     x16, wq16, wo16, w116, w216);
    k_gemm<0><<<dim3(256, 12),     256, 0, stream>>>(x16, wq16, bqkv, 256,
                                                     qb16, kb16, vt16, nullptr, nullptr);
    k_flashL <<<dim3(32, H, B),    256, 0, stream>>>(qb16, kb16, mask, liout);
    k_flashPV<<<dim3(64, H, B),    256, 0, stream>>>(qb16, kb16, vt16, mask, liout,
                                                     opart, part4);
    k_comb   <<<dim3(2048),        256, 0, stream>>>(opart, attn16);
    k_red    <<<dim3(16, B),       256, 0, stream>>>(part4, redb);
    k_halt   <<<dim3(B),           256, 0, stream>>>(redb, mask, outh);
    k_gemm<1><<<dim3(256, 4),      256, 0, stream>>>(attn16, wo16, bo, 256,
                                                     nullptr, nullptr, nullptr, po, nullptr);
    k_ln     <<<dim3(B*T/16),      256, 0, stream>>>(x, po, g1, be1, hb, h16);
    k_gemm<2><<<dim3(256, 16),     256, 0, stream>>>(h16, w116, b1, 256,
                                                     nullptr, nullptr, nullptr, nullptr, mid16);
    k_gemm<3><<<dim3(256, 4),      256, 0, stream>>>(mid16, w216, b2, 1024,
                                                     nullptr, nullptr, nullptr, fo, nullptr);
    k_ln     <<<dim3(B*T/16),      256, 0, stream>>>(hb, fo, g2, be2, out, nullptr);
}

// Round 8
// 230.579 us; speedup vs baseline: 2.6978x; 2.6978x over previous
//
#include <hip/hip_runtime.h>
#include <hip/hip_bf16.h>
#include <math.h>

namespace {

constexpr int B = 8, T = 2048, D = 256, H = 4, HD = 64, FF = 1024;
constexpr float QSCALE = 0.18033688f;   // 0.125 * log2(e)

typedef __attribute__((ext_vector_type(8))) short short8;
typedef __attribute__((ext_vector_type(4))) short s16x4;
typedef __attribute__((ext_vector_type(4))) float f32x4;

__device__ __forceinline__ short f2bf(float f) {
    __hip_bfloat16 h = __float2bfloat16(f);
    return *reinterpret_cast<short*>(&h);
}
__device__ __forceinline__ float exp2a(float x) {
    float r; asm("v_exp_f32 %0, %1" : "=v"(r) : "v"(x)); return r;
}
__device__ __forceinline__ unsigned cvtpk(float lo, float hi) {
    unsigned r; asm("v_cvt_pk_bf16_f32 %0, %1, %2" : "=v"(r) : "v"(lo), "v"(hi)); return r;
}

// ---------------- K0: fp32 -> bf16 conversions (x + 4 weight matrices) -----
__global__ __launch_bounds__(256) void k_cvt(
        const float* __restrict__ x,  const float* __restrict__ wq,
        const float* __restrict__ wo, const float* __restrict__ w1,
        const float* __restrict__ w2,
        short* __restrict__ x16,  short* __restrict__ wq16,
        short* __restrict__ wo16, short* __restrict__ w116,
        short* __restrict__ w216) {
    const int N0 = 524288, N1 = 24576, N2 = 8192, N3 = 32768, N4 = 32768;
    const int total = N0 + N1 + N2 + N3 + N4;
    for (int i = blockIdx.x*256 + threadIdx.x; i < total; i += gridDim.x*256) {
        const float* s; short* d; int j = i;
        if (j < N0) { s = x; d = x16; }
        else { j -= N0;
            if (j < N1) { s = wq; d = wq16; }
            else { j -= N1;
                if (j < N2) { s = wo; d = wo16; }
                else { j -= N2;
                    if (j < N3) { s = w1; d = w116; }
                    else { j -= N3; s = w2; d = w216; }
                }
            }
        }
        float4 a = ((const float4*)s)[j*2], b2 = ((const float4*)s)[j*2+1];
        short8 o;
        o[0]=f2bf(a.x);  o[1]=f2bf(a.y);  o[2]=f2bf(a.z);  o[3]=f2bf(a.w);
        o[4]=f2bf(b2.x); o[5]=f2bf(b2.y); o[6]=f2bf(b2.z); o[7]=f2bf(b2.w);
        ((short8*)d)[j] = o;
    }
}

// ---------------- K_GEMM: R6-proven LDS-staged bf16 MFMA GEMM --------------
template<int MODE>
__global__ __launch_bounds__(256) void k_gemm(
        const short* __restrict__ A, const short* __restrict__ W,
        const float* __restrict__ bias, const int K,
        short* __restrict__ oq, short* __restrict__ ok, short* __restrict__ ov,
        float* __restrict__ of, short* __restrict__ o16) {
    __shared__ short As[64][72];
    __shared__ short Ws[64][72];
    __shared__ float Cs[64][68];
    const int tid = threadIdx.x;
    const int w = tid >> 6, lane = tid & 63;
    const int qr = lane & 15, g = lane >> 4;
    const int wm = w >> 1, wn = w & 1;
    const int m0 = blockIdx.x * 64;
    const int n0 = blockIdx.y * 64;
    const int srow = tid >> 2, scol = (tid & 3) * 8;
    const short* Ag = A + (size_t)(m0 + srow) * K + scol;
    const short* Wg = W + (size_t)(n0 + srow) * K + scol;

    f32x4 acc[2][2];
    #pragma unroll
    for (int i = 0; i < 2; i++)
        #pragma unroll
        for (int j = 0; j < 2; j++) acc[i][j] = (f32x4){0.f, 0.f, 0.f, 0.f};

    for (int k0 = 0; k0 < K; k0 += 64) {
        __syncthreads();
        *(short8*)&As[srow][scol]      = *(const short8*)(Ag + k0);
        *(short8*)&As[srow][scol + 32] = *(const short8*)(Ag + k0 + 32);
        *(short8*)&Ws[srow][scol]      = *(const short8*)(Wg + k0);
        *(short8*)&Ws[srow][scol + 32] = *(const short8*)(Wg + k0 + 32);
        __syncthreads();
        #pragma unroll
        for (int kk = 0; kk < 2; kk++) {
            short8 a0 = *(const short8*)&As[wm*32 + qr][g*8 + kk*32];
            short8 a1 = *(const short8*)&As[wm*32 + 16 + qr][g*8 + kk*32];
            short8 b0 = *(const short8*)&Ws[wn*32 + qr][g*8 + kk*32];
            short8 b1 = *(const short8*)&Ws[wn*32 + 16 + qr][g*8 + kk*32];
            acc[0][0] = __builtin_amdgcn_mfma_f32_16x16x32_bf16(a0, b0, acc[0][0], 0, 0, 0);
            acc[0][1] = __builtin_amdgcn_mfma_f32_16x16x32_bf16(a0, b1, acc[0][1], 0, 0, 0);
            acc[1][0] = __builtin_amdgcn_mfma_f32_16x16x32_bf16(a1, b0, acc[1][0], 0, 0, 0);
            acc[1][1] = __builtin_amdgcn_mfma_f32_16x16x32_bf16(a1, b1, acc[1][1], 0, 0, 0);
        }
    }

    const int b = m0 >> 11;
    const int tl0 = m0 & (T - 1);

    if (MODE == 0 && blockIdx.y >= 8) {
        const int h = (int)blockIdx.y - 8;
        #pragma unroll
        for (int fm = 0; fm < 2; fm++) {
            const int tbase = tl0 + wm*32 + fm*16 + g*4;
            #pragma unroll
            for (int fn = 0; fn < 2; fn++) {
                const int d = wn*32 + fn*16 + qr;
                const float bv = bias[n0 + d];
                s16x4 pk;
                #pragma unroll
                for (int r = 0; r < 4; r++) pk[r] = f2bf(acc[fm][fn][r] + bv);
                *(s16x4*)&ov[((size_t)(b*H + h)*HD + d)*T + tbase] = pk;
            }
        }
        return;
    }

    #pragma unroll
    for (int fm = 0; fm < 2; fm++)
        #pragma unroll
        for (int fn = 0; fn < 2; fn++)
            #pragma unroll
            for (int r = 0; r < 4; r++)
                Cs[wm*32 + fm*16 + g*4 + r][wn*32 + fn*16 + qr] = acc[fm][fn][r];
    __syncthreads();
    const int row = tid >> 2, c0 = (tid & 3) * 16;
    float vals[16];
    #pragma unroll
    for (int j = 0; j < 16; j++) vals[j] = Cs[row][c0 + j] + bias[n0 + c0 + j];

    if (MODE == 0) {
        const int by = blockIdx.y;
        short* dst = (by < 4) ? oq : ok;
        const float qs = (by < 4) ? QSCALE : 1.0f;
        const int h = by & 3;
        short8 s0, s1;
        #pragma unroll
        for (int j = 0; j < 8; j++) { s0[j] = f2bf(vals[j]*qs); s1[j] = f2bf(vals[8+j]*qs); }
        short* p = dst + ((size_t)(b*H + h)*T + tl0 + row)*HD + c0;
        *(short8*)p = s0;
        *(short8*)(p + 8) = s1;
    } else if (MODE == 1 || MODE == 3) {
        float* p = of + (size_t)(m0 + row)*256 + n0 + c0;
        #pragma unroll
        for (int jj = 0; jj < 4; jj++) *(float4*)(p + jj*4) = *(float4*)&vals[jj*4];
    } else {
        short8 s0, s1;
        #pragma unroll
        for (int j = 0; j < 8; j++) {
            s0[j] = f2bf(fmaxf(vals[j], 0.f));
            s1[j] = f2bf(fmaxf(vals[8+j], 0.f));
        }
        short* p = o16 + (size_t)(m0 + row)*1024 + n0 + c0;
        *(short8*)p = s0;
        *(short8*)(p + 8) = s1;
    }
}

// ---------------- FL: l-only pass. Wave-private K staging, NO barriers. ----
// Waves partition keys: wave w handles keys w*32..w*32+31 of each 128-tile,
// for ALL 64 q of the block. Per-wave l partials reduced at the end.
__global__ __launch_bounds__(256) void k_flashL(
        const short* __restrict__ qb, const short* __restrict__ kb,
        const float* __restrict__ mask, float* __restrict__ liout) {
    __shared__ short Ks[128][72];
    __shared__ float lbuf[4][4][16];
    const int tid = threadIdx.x;
    const int w = tid >> 6, lane = tid & 63;
    const int qr = lane & 15, g = lane >> 4;
    const int qt = blockIdx.x, h = blockIdx.y, b = blockIdx.z;
    const int bh = b*H + h;
    const int q0 = qt*64;

    short8 qf[4][2];
    {
        const short* qg = qb + ((size_t)bh * T + q0) * HD;
        #pragma unroll
        for (int qt4 = 0; qt4 < 4; qt4++) {
            qf[qt4][0] = *(const short8*)(qg + (qt4*16 + qr)*HD + g*8);
            qf[qt4][1] = *(const short8*)(qg + (qt4*16 + qr)*HD + 32 + g*8);
        }
    }
    const short* kg0 = kb + (size_t)bh * T * HD;
    const float* mg  = mask + (size_t)b * T;
    const int krow = lane >> 1, khalf = (lane & 1) * 32;

    float lrun[4] = {0.f, 0.f, 0.f, 0.f};

    for (int kt = 0; kt < 16; kt++) {
        const int kbase = kt*128 + w*32;
        {
            const short* ksrc = kg0 + (size_t)(kbase + krow)*HD + khalf;
            short* kdst = &Ks[w*32 + krow][khalf];
            #pragma unroll
            for (int c = 0; c < 4; c++)
                *(short8*)(kdst + c*8) = *(const short8*)(ksrc + c*8);
        }
        asm volatile("" ::: "memory");
        #pragma unroll
        for (int kt2 = 0; kt2 < 2; kt2++) {
            short8 kf0 = *(const short8*)&Ks[w*32 + kt2*16 + qr][g*8];
            short8 kf1 = *(const short8*)&Ks[w*32 + kt2*16 + qr][g*8 + 32];
            const int key0 = kbase + kt2*16;
            const float4 mv4 = *(const float4*)(mg + key0 + 4*g);
            const float b0 = (mv4.x > 0.5f) ? -1e9f : 0.f;
            const float b1 = (mv4.y > 0.5f) ? -1e9f : 0.f;
            const float b2v = (mv4.z > 0.5f) ? -1e9f : 0.f;
            const float b3 = (mv4.w > 0.5f) ? -1e9f : 0.f;
            #pragma unroll
            for (int qt4 = 0; qt4 < 4; qt4++) {
                f32x4 sa = (f32x4){b0, b1, b2v, b3};
                sa = __builtin_amdgcn_mfma_f32_16x16x32_bf16(kf0, qf[qt4][0], sa, 0, 0, 0);
                sa = __builtin_amdgcn_mfma_f32_16x16x32_bf16(kf1, qf[qt4][1], sa, 0, 0, 0);
                lrun[qt4] += (exp2a(sa[0]) + exp2a(sa[1])) + (exp2a(sa[2]) + exp2a(sa[3]));
            }
        }
        asm volatile("" ::: "memory");
    }
    #pragma unroll
    for (int qt4 = 0; qt4 < 4; qt4++) {
        lrun[qt4] += __shfl_xor(lrun[qt4], 16, 64);
        lrun[qt4] += __shfl_xor(lrun[qt4], 32, 64);
    }
    if (g == 0) {
        #pragma unroll
        for (int qt4 = 0; qt4 < 4; qt4++) lbuf[w][qt4][qr] = lrun[qt4];
    }
    __syncthreads();
    if (tid < 64) {
        const int qt4 = tid >> 4, qrr = tid & 15;
        const float l = lbuf[0][qt4][qrr] + lbuf[1][qt4][qrr]
                      + lbuf[2][qt4][qrr] + lbuf[3][qt4][qrr];
        liout[(size_t)bh*T + q0 + tid] = -__log2f(l);
    }
}

// ---------------- FATTN: QK+PV+colsum fused. Wave-private staging,
// barrier-free K-loop, li-folded normalized P (R7-validated numerics). -----
__global__ __launch_bounds__(256) void k_fattn(
        const short* __restrict__ qb, const short* __restrict__ kb,
        const short* __restrict__ vtb, const float* __restrict__ mask,
        const float* __restrict__ liout,
        short* __restrict__ attnb, float* __restrict__ part4) {
    __shared__ short Ks[128][72];     // 18432 B
    __shared__ short Vt[64][136];     // 17408 B
    __shared__ short Ps[4][64][40];   // 20480 B  (wave-private P[q][keylocal])
    const int tid = threadIdx.x;
    const int w = tid >> 6, lane = tid & 63;
    const int qr = lane & 15, g = lane >> 4;
    const int qt = blockIdx.x, h = blockIdx.y, b = blockIdx.z;
    const int bh = b*H + h;
    const int q0 = qt*64;

    short8 qf[4][2];
    float li[4];
    {
        const short* qg = qb + ((size_t)bh * T + q0) * HD;
        #pragma unroll
        for (int qt4 = 0; qt4 < 4; qt4++) {
            qf[qt4][0] = *(const short8*)(qg + (qt4*16 + qr)*HD + g*8);
            qf[qt4][1] = *(const short8*)(qg + (qt4*16 + qr)*HD + 32 + g*8);
            li[qt4] = liout[(size_t)bh*T + q0 + qt4*16 + qr];
        }
    }
    const short* kg0 = kb + (size_t)bh * T * HD;
    const short* vg0 = vtb + (size_t)bh * HD * T;
    const float* mg  = mask + (size_t)b * T;
    float* csrow = part4 + (size_t)(bh*32 + qt) * T;
    const int krow = lane >> 1, khalf = (lane & 1) * 32;

    f32x4 oa[4][4];
    #pragma unroll
    for (int nt = 0; nt < 4; nt++)
        #pragma unroll
        for (int qt4 = 0; qt4 < 4; qt4++) oa[nt][qt4] = (f32x4){0.f,0.f,0.f,0.f};

    short8 kreg[4], vreg[4];
    // prologue: stage tile 0
    #pragma unroll
    for (int c = 0; c < 4; c++) {
        kreg[c] = *(const short8*)(kg0 + (size_t)(w*32 + krow)*HD + khalf + c*8);
        vreg[c] = *(const short8*)(vg0 + (size_t)lane*T + w*32 + c*8);
    }
    #pragma unroll
    for (int c = 0; c < 4; c++) {
        *(short8*)&Ks[w*32 + krow][khalf + c*8] = kreg[c];
        *(short8*)&Vt[lane][w*32 + c*8] = vreg[c];
    }
    asm volatile("" ::: "memory");

    for (int kt = 0; kt < 16; kt++) {
        // T14: issue next tile's global loads before computing current
        if (kt < 15) {
            const int nb = (kt+1)*128 + w*32;
            #pragma unroll
            for (int c = 0; c < 4; c++) {
                kreg[c] = *(const short8*)(kg0 + (size_t)(nb + krow)*HD + khalf + c*8);
                vreg[c] = *(const short8*)(vg0 + (size_t)lane*T + nb + c*8);
            }
        }
        const int kbase = kt*128 + w*32;
        // QK^T + exp2 + colsum + P repack
        #pragma unroll
        for (int kt2 = 0; kt2 < 2; kt2++) {
            short8 kf0 = *(const short8*)&Ks[w*32 + kt2*16 + qr][g*8];
            short8 kf1 = *(const short8*)&Ks[w*32 + kt2*16 + qr][g*8 + 32];
            const int key0 = kbase + kt2*16;
            const float4 mv4 = *(const float4*)(mg + key0 + 4*g);
            const float mb[4] = { (mv4.x > 0.5f) ? -1e9f : 0.f,
                                  (mv4.y > 0.5f) ? -1e9f : 0.f,
                                  (mv4.z > 0.5f) ? -1e9f : 0.f,
                                  (mv4.w > 0.5f) ? -1e9f : 0.f };
            float p[4][4];
            #pragma unroll
            for (int qt4 = 0; qt4 < 4; qt4++) {
                f32x4 sa = (f32x4){mb[0] + li[qt4], mb[1] + li[qt4],
                                   mb[2] + li[qt4], mb[3] + li[qt4]};
                sa = __builtin_amdgcn_mfma_f32_16x16x32_bf16(kf0, qf[qt4][0], sa, 0, 0, 0);
                sa = __builtin_amdgcn_mfma_f32_16x16x32_bf16(kf1, qf[qt4][1], sa, 0, 0, 0);
                p[qt4][0] = exp2a(sa[0]); p[qt4][1] = exp2a(sa[1]);
                p[qt4][2] = exp2a(sa[2]); p[qt4][3] = exp2a(sa[3]);
            }
            // colsum over this block's 64 q for keys key0+4g+r
            float cs[4];
            #pragma unroll
            for (int r = 0; r < 4; r++) {
                cs[r] = (p[0][r] + p[1][r]) + (p[2][r] + p[3][r]);
                cs[r] += __shfl_xor(cs[r], 1, 64);
                cs[r] += __shfl_xor(cs[r], 2, 64);
                cs[r] += __shfl_xor(cs[r], 4, 64);
                cs[r] += __shfl_xor(cs[r], 8, 64);
            }
            if (qr == 0) {
                #pragma unroll
                for (int r = 0; r < 4; r++) csrow[key0 + 4*g + r] = cs[r];
            }
            // repack P -> Ps (normalized bf16)
            #pragma unroll
            for (int qt4 = 0; qt4 < 4; qt4++) {
                union { unsigned u[2]; s16x4 s; } cv;
                cv.u[0] = cvtpk(p[qt4][0], p[qt4][1]);
                cv.u[1] = cvtpk(p[qt4][2], p[qt4][3]);
                *(s16x4*)&Ps[w][qt4*16 + qr][kt2*16 + 4*g] = cv.s;
            }
        }
        asm volatile("" ::: "memory");
        // PV over the wave's 32 keys (single K=32 MFMA per (nt,qt4))
        short8 pa[4];
        #pragma unroll
        for (int qt4 = 0; qt4 < 4; qt4++)
            pa[qt4] = *(const short8*)&Ps[w][qt4*16 + qr][g*8];
        #pragma unroll
        for (int nt = 0; nt < 4; nt++) {
            short8 vf = *(const short8*)&Vt[nt*16 + qr][w*32 + g*8];
            #pragma unroll
            for (int qt4 = 0; qt4 < 4; qt4++)
                oa[nt][qt4] = __builtin_amdgcn_mfma_f32_16x16x32_bf16(vf, pa[qt4], oa[nt][qt4], 0, 0, 0);
        }
        // write next tile into (wave-private) LDS after all reads of current
        if (kt < 15) {
            asm volatile("" ::: "memory");
            #pragma unroll
            for (int c = 0; c < 4; c++) {
                *(short8*)&Ks[w*32 + krow][khalf + c*8] = kreg[c];
                *(short8*)&Vt[lane][w*32 + c*8] = vreg[c];
            }
            asm volatile("" ::: "memory");
        }
    }

    // ---- O reduction across waves (Obuf overlays Ks) ----
    __syncthreads();
    float* Obuf = (float*)&Ks[0][0];   // [4 w][16 d][68 q-stride]
    const int qL = tid >> 2, dq = tid & 3;
    #pragma unroll
    for (int nt = 0; nt < 4; nt++) {
        #pragma unroll
        for (int qt4 = 0; qt4 < 4; qt4++)
            #pragma unroll
            for (int r = 0; r < 4; r++)
                Obuf[(w*16 + 4*g + r)*68 + qt4*16 + qr] = oa[nt][qt4][r];
        __syncthreads();
        s16x4 pk;
        #pragma unroll
        for (int rr = 0; rr < 4; rr++) {
            const int dr = dq*4 + rr;
            float v = Obuf[(0*16 + dr)*68 + qL] + Obuf[(1*16 + dr)*68 + qL]
                    + Obuf[(2*16 + dr)*68 + qL] + Obuf[(3*16 + dr)*68 + qL];
            pk[rr] = f2bf(v);
        }
        *(s16x4*)&attnb[((size_t)b*T + q0 + qL)*D + h*HD + nt*16 + dq*4] = pk;
        __syncthreads();
    }
}

// ---------------- K_RED: red[b][k] = sum over 128 (h,qt) rows of part ------
__global__ __launch_bounds__(256) void k_red(
        const float* __restrict__ part, float* __restrict__ red) {
    __shared__ float s[128];
    const int b = blockIdx.y, kc = blockIdx.x;
    const int tid = threadIdx.x;
    const int c = tid & 127, half = tid >> 7;
    const int k = kc*128 + c;
    const float* pb = part + ((size_t)(b*128 + half*64))*T + k;
    float acc = 0.f;
    #pragma unroll 8
    for (int r = 0; r < 64; r++) acc += pb[(size_t)r*T];
    if (half) s[c] = acc;
    __syncthreads();
    if (!half) red[(size_t)b*T + k] = acc + s[c];
}

// ---------------- K3: halting = softmax(red/H + mask*(-1e10)) --------------
__global__ __launch_bounds__(256) void k_halt(
        const float* __restrict__ red, const float* __restrict__ mask,
        float* __restrict__ outh) {
    __shared__ float redm[4], reds[4];
    const int b = blockIdx.x, tid = threadIdx.x;
    const float* mg = mask + (size_t)b * T;
    float v[8];
    float M = -3e38f;
    #pragma unroll
    for (int i = 0; i < 8; i++) {
        v[i] = red[(size_t)b*T + tid + i*256]*0.25f + mg[tid + i*256]*(-1e10f);
        M = fmaxf(M, v[i]);
    }
    #pragma unroll
    for (int off = 1; off < 64; off <<= 1) M = fmaxf(M, __shfl_xor(M, off, 64));
    const int wv = tid >> 6, lane = tid & 63;
    if (lane == 0) redm[wv] = M;
    __syncthreads();
    M = fmaxf(fmaxf(redm[0], redm[1]), fmaxf(redm[2], redm[3]));
    float S = 0.f;
    #pragma unroll
    for (int i = 0; i < 8; i++) { v[i] = __expf(v[i] - M); S += v[i]; }
    #pragma unroll
    for (int off = 1; off < 64; off <<= 1) S += __shfl_xor(S, off, 64);
    if (lane == 0) reds[wv] = S;
    __syncthreads();
    const float invS = 1.f / (reds[0] + reds[1] + reds[2] + reds[3]);
    #pragma unroll
    for (int i = 0; i < 8; i++) outh[(size_t)b*T + tid + i*256] = v[i]*invS;
}

// ---------------- K_LN: y = LN(a + bsrc)*g + be; optional bf16 copy --------
__global__ __launch_bounds__(256) void k_ln(
        const float* __restrict__ a, const float* __restrict__ bsrc,
        const float* __restrict__ g, const float* __restrict__ be,
        float* __restrict__ yf, short* __restrict__ y16) {
    __shared__ float s[16][D];
    const int tid = threadIdx.x;
    const size_t row0 = (size_t)blockIdx.x * 16;
    const float4* ag = (const float4*)(a + row0*D);
    const float4* bg = (const float4*)(bsrc + row0*D);
    #pragma unroll
    for (int i = 0; i < 4; i++) {
        float4 av = ag[tid + i*256], bv = bg[tid + i*256];
        float4 sv = {av.x+bv.x, av.y+bv.y, av.z+bv.z, av.w+bv.w};
        ((float4*)&s[0][0])[tid + i*256] = sv;
    }
    __syncthreads();
    const int wv = tid >> 6, lane = tid & 63;
    float gvv[4], bvv[4];
    #pragma unroll
    for (int s2 = 0; s2 < 4; s2++) { gvv[s2] = g[lane + 64*s2]; bvv[s2] = be[lane + 64*s2]; }
    #pragma unroll
    for (int rr = 0; rr < 4; rr++) {
        const int r = wv*4 + rr;
        float x0 = s[r][lane],     x1 = s[r][lane+64];
        float x2 = s[r][lane+128], x3 = s[r][lane+192];
        float sum = x0+x1+x2+x3;
        float ssq = x0*x0 + x1*x1 + x2*x2 + x3*x3;
        #pragma unroll
        for (int off = 1; off < 64; off <<= 1) {
            sum += __shfl_xor(sum, off, 64);
            ssq += __shfl_xor(ssq, off, 64);
        }
        const float mu = sum * (1.f/256.f);
        const float rs = rsqrtf(ssq*(1.f/256.f) - mu*mu + 1e-5f);
        float y0 = (x0 - mu)*rs*gvv[0] + bvv[0];
        float y1 = (x1 - mu)*rs*gvv[1] + bvv[1];
        float y2 = (x2 - mu)*rs*gvv[2] + bvv[2];
        float y3 = (x3 - mu)*rs*gvv[3] + bvv[3];
        float* yp = yf + (row0 + r)*D;
        yp[lane]     = y0;
        yp[lane+64]  = y1;
        yp[lane+128] = y2;
        yp[lane+192] = y3;
        if (y16) {
            short* hp = y16 + (row0 + r)*D;
            hp[lane]     = f2bf(y0);
            hp[lane+64]  = f2bf(y1);
            hp[lane+128] = f2bf(y2);
            hp[lane+192] = f2bf(y3);
        }
    }
}

} // namespace

extern "C" void kernel_launch(void* const* d_in, const int* in_sizes, int n_in,
                              void* d_out, int out_size, void* d_ws, size_t ws_size,
                              hipStream_t stream) {
    (void)in_sizes; (void)n_in; (void)out_size; (void)ws_size;
    const float* x    = (const float*)d_in[0];
    const float* mask = (const float*)d_in[1];
    const float* Wqkv = (const float*)d_in[2];
    const float* bqkv = (const float*)d_in[3];
    const float* Wo   = (const float*)d_in[4];
    const float* bo   = (const float*)d_in[5];
    const float* W1   = (const float*)d_in[6];
    const float* b1   = (const float*)d_in[7];
    const float* W2   = (const float*)d_in[8];
    const float* b2   = (const float*)d_in[9];
    const float* g1   = (const float*)d_in[10];
    const float* be1  = (const float*)d_in[11];
    const float* g2   = (const float*)d_in[12];
    const float* be2  = (const float*)d_in[13];

    float* out  = (float*)d_out;
    char*  wsb  = (char*)d_ws;
    const size_t MB = 1024*1024;

    // liveness-overlaid layout, top = 84 MiB (>=96 MiB proven)
    short* qb16   = (short*)(wsb + 0*MB);            // gemm0 -> fattn
    short* kb16   = (short*)(wsb + 8*MB);            // gemm0 -> fattn
    short* vt16   = (short*)(wsb + 16*MB);           // gemm0 -> fattn
    short* x16    = (short*)(wsb + 24*MB);           // cvt -> gemm0
    short* attn16 = (short*)(wsb + 24*MB);           // fattn -> gemm1 (x16 dead)
    short* mid16  = (short*)(wsb + 0*MB);            // gemm2 -> gemm3 (q/k/v/attn dead)
    float* part4  = (float*)(wsb + 32*MB);           // 8MB, fattn -> red
    float* redb   = (float*)(wsb + 40*MB);           // 64KB, red -> halt
    float* liout  = (float*)(wsb + 41*MB);           // 256KB, flashL -> fattn
    short* wq16   = (short*)(wsb + 42*MB);
    short* wo16   = (short*)(wsb + 42*MB + 393216);
    short* w116   = (short*)(wsb + 42*MB + 524288);
    short* w216   = (short*)(wsb + 42*MB + 1048576);
    float* hb     = (float*)(wsb + 44*MB);           // ln1 -> ln2
    short* h16    = (short*)(wsb + 60*MB);           // ln1 -> gemm2
    float* po     = (float*)(wsb + 68*MB);           // gemm1 -> ln1
    float* fo     = (float*)(wsb + 68*MB);           // gemm3 -> ln2 (po dead)
    float* outh   = out + (size_t)B*T*D;

    k_cvt    <<<dim3(1024),        256, 0, stream>>>(x, Wqkv, Wo, W1, W2,
                                                     x16, wq16, wo16, w116, w216);
    k_gemm<0><<<dim3(256, 12),     256, 0, stream>>>(x16, wq16, bqkv, 256,
                                                     qb16, kb16, vt16, nullptr, nullptr);
    k_flashL <<<dim3(32, H, B),    256, 0, stream>>>(qb16, kb16, mask, liout);
    k_fattn  <<<dim3(32, H, B),    256, 0, stream>>>(qb16, kb16, vt16, mask, liout,
                                                     attn16, part4);
    k_red    <<<dim3(16, B),       256, 0, stream>>>(part4, redb);
    k_halt   <<<dim3(B),           256, 0, stream>>>(redb, mask, outh);
    k_gemm<1><<<dim3(256, 4),      256, 0, stream>>>(attn16, wo16, bo, 256,
                                                     nullptr, nullptr, nullptr, po, nullptr);
    k_ln     <<<dim3(B*T/16),      256, 0, stream>>>(x, po, g1, be1, hb, h16);
    k_gemm<2><<<dim3(256, 16),     256, 0, stream>>>(h16, w116, b1, 256,
                                                     nullptr, nullptr, nullptr, nullptr, mid16);
    k_gemm<3><<<dim3(256, 4),      256, 0, stream>>>(mid16, w216, b2, 1024,
                                                     nullptr, nullptr, nullptr, fo, nullptr);
    k_ln     <<<dim3(B*T/16),      256, 0, stream>>>(hb, fo, g2, be2, out, nullptr);
}